// Round 1
// baseline (5815.135 us; speedup 1.0000x reference)
//
#include <hip/hip_runtime.h>
#include <cstdint>

#define Eexp 8
#define Bb   16384
#define Dd   512
#define Hh   512
#define Zz   64

// ---------------------------------------------------------------------------
// SGEMM: C = (A @ W + bias), optional ReLU.  A[M,K] row-major, W[K,N] row-major.
// BM=128, BK=16, 256 threads. BN=128 -> 8x8 micro (split halves), BN=64 -> 8x4.
// ---------------------------------------------------------------------------
template<int BN, bool RELU>
__global__ __launch_bounds__(256, 2)
void sgemm_bias(const float* __restrict__ A, const float* __restrict__ W,
                const float* __restrict__ bias, float* __restrict__ C,
                int M, int N, int K)
{
    constexpr int BM = 128, BK = 16;
    constexpr int NH = (BN == 128) ? 2 : 1;   // column halves
    __shared__ float As[BK][BM];
    __shared__ float Bs[BK][BN];

    const int tid = threadIdx.x;
    const int tx  = tid & 15;     // 0..15 -> cols tx*4 (+64)
    const int ty  = tid >> 4;     // 0..15 -> rows ty*4 (+64)
    const int rowBase = blockIdx.x * BM;
    const int colBase = blockIdx.y * BN;

    float acc[8][NH * 4];
    #pragma unroll
    for (int i = 0; i < 8; ++i)
        #pragma unroll
        for (int j = 0; j < NH * 4; ++j) acc[i][j] = 0.f;

    for (int k0 = 0; k0 < K; k0 += BK) {
        __syncthreads();
        // A tile: 128 rows x 16 cols = 512 float4, transposed into As[k][m]
        #pragma unroll
        for (int it = 0; it < 2; ++it) {
            const int idx = tid + it * 256;
            const int ar  = idx >> 2;
            const int ac4 = idx & 3;
            const float4 v = *reinterpret_cast<const float4*>(
                &A[(size_t)(rowBase + ar) * K + k0 + ac4 * 4]);
            As[ac4 * 4 + 0][ar] = v.x;
            As[ac4 * 4 + 1][ar] = v.y;
            As[ac4 * 4 + 2][ar] = v.z;
            As[ac4 * 4 + 3][ar] = v.w;
        }
        // B tile: 16 rows x BN cols
        #pragma unroll
        for (int it = 0; it < BN / 64; ++it) {
            const int idx = tid + it * 256;
            const int br  = idx / (BN / 4);
            const int bc4 = idx % (BN / 4);
            *reinterpret_cast<float4*>(&Bs[br][bc4 * 4]) =
                *reinterpret_cast<const float4*>(
                    &W[(size_t)(k0 + br) * N + colBase + bc4 * 4]);
        }
        __syncthreads();

        #pragma unroll
        for (int kk = 0; kk < BK; ++kk) {
            float a[8], b[NH * 4];
            const float4 a0 = *reinterpret_cast<const float4*>(&As[kk][ty * 4]);
            const float4 a1 = *reinterpret_cast<const float4*>(&As[kk][64 + ty * 4]);
            a[0] = a0.x; a[1] = a0.y; a[2] = a0.z; a[3] = a0.w;
            a[4] = a1.x; a[5] = a1.y; a[6] = a1.z; a[7] = a1.w;
            const float4 b0 = *reinterpret_cast<const float4*>(&Bs[kk][tx * 4]);
            b[0] = b0.x; b[1] = b0.y; b[2] = b0.z; b[3] = b0.w;
            if constexpr (NH == 2) {
                const float4 b1 = *reinterpret_cast<const float4*>(&Bs[kk][64 + tx * 4]);
                b[4] = b1.x; b[5] = b1.y; b[6] = b1.z; b[7] = b1.w;
            }
            #pragma unroll
            for (int i = 0; i < 8; ++i)
                #pragma unroll
                for (int j = 0; j < NH * 4; ++j)
                    acc[i][j] = fmaf(a[i], b[j], acc[i][j]);
        }
    }

    // epilogue: bias (+ReLU), coalesced float4 stores
    const float4 bias0 = *reinterpret_cast<const float4*>(&bias[colBase + tx * 4]);
    float4 bias1 = bias0;
    if constexpr (NH == 2)
        bias1 = *reinterpret_cast<const float4*>(&bias[colBase + 64 + tx * 4]);

    #pragma unroll
    for (int i = 0; i < 8; ++i) {
        const int rl  = (i < 4) ? (ty * 4 + i) : (64 + ty * 4 + (i - 4));
        const int row = rowBase + rl;
        float4 v0;
        v0.x = acc[i][0] + bias0.x;
        v0.y = acc[i][1] + bias0.y;
        v0.z = acc[i][2] + bias0.z;
        v0.w = acc[i][3] + bias0.w;
        if constexpr (RELU) {
            v0.x = fmaxf(v0.x, 0.f); v0.y = fmaxf(v0.y, 0.f);
            v0.z = fmaxf(v0.z, 0.f); v0.w = fmaxf(v0.w, 0.f);
        }
        *reinterpret_cast<float4*>(&C[(size_t)row * N + colBase + tx * 4]) = v0;
        if constexpr (NH == 2) {
            float4 v1;
            v1.x = acc[i][4] + bias1.x;
            v1.y = acc[i][5] + bias1.y;
            v1.z = acc[i][6] + bias1.z;
            v1.w = acc[i][7] + bias1.w;
            if constexpr (RELU) {
                v1.x = fmaxf(v1.x, 0.f); v1.y = fmaxf(v1.y, 0.f);
                v1.z = fmaxf(v1.z, 0.f); v1.w = fmaxf(v1.w, 0.f);
            }
            *reinterpret_cast<float4*>(&C[(size_t)row * N + colBase + 64 + tx * 4]) = v1;
        }
    }
}

// z = mu + exp(0.5*logvar)*eps, over B*Z floats as float4
__global__ __launch_bounds__(256)
void z_kernel(const float4* __restrict__ mu, const float4* __restrict__ lv,
              const float4* __restrict__ eps, float4* __restrict__ z)
{
    const int i = blockIdx.x * 256 + threadIdx.x;
    const float4 m = mu[i], l = lv[i], e = eps[i];
    float4 r;
    r.x = m.x + expf(0.5f * l.x) * e.x;
    r.y = m.y + expf(0.5f * l.y) * e.y;
    r.z = m.z + expf(0.5f * l.z) * e.z;
    r.w = m.w + expf(0.5f * l.w) * e.w;
    z[i] = r;
}

// recon[b] = mean_d (xhat[b,d]-x[b,d])^2 ; one wave per row, 4 rows/block
__global__ __launch_bounds__(256)
void recon_kernel(const float* __restrict__ xhat, const float* __restrict__ x,
                  float* __restrict__ recon)
{
    const int wave = threadIdx.x >> 6;
    const int lane = threadIdx.x & 63;
    const int row  = blockIdx.x * 4 + wave;
    const float4* xh = reinterpret_cast<const float4*>(&xhat[(size_t)row * Dd]);
    const float4* xx = reinterpret_cast<const float4*>(&x[(size_t)row * Dd]);
    float s = 0.f;
    #pragma unroll
    for (int it = 0; it < 2; ++it) {
        const float4 a = xh[lane + it * 64];
        const float4 b = xx[lane + it * 64];
        float d;
        d = a.x - b.x; s = fmaf(d, d, s);
        d = a.y - b.y; s = fmaf(d, d, s);
        d = a.z - b.z; s = fmaf(d, d, s);
        d = a.w - b.w; s = fmaf(d, d, s);
    }
    #pragma unroll
    for (int off = 32; off > 0; off >>= 1) s += __shfl_down(s, off);
    if (lane == 0) recon[row] = s * (1.0f / 512.0f);
}

// running-min select: rows where recon_e < best get their outputs overwritten.
// strict '<' == jnp.argmin first-index tie-break. isFirst forces write (init).
__global__ __launch_bounds__(256)
void select_kernel(const float* __restrict__ recon, float* __restrict__ best,
                   const float* __restrict__ mu_e, const float* __restrict__ lv_e,
                   const float* __restrict__ xhat,
                   float* __restrict__ out_mu, float* __restrict__ out_lv,
                   float* __restrict__ out_xh, int isFirst)
{
    const int wave = threadIdx.x >> 6;
    const int lane = threadIdx.x & 63;
    const int row  = blockIdx.x * 4 + wave;
    const float r  = recon[row];
    const bool cond = isFirst || (r < best[row]);
    if (cond) {
        if (lane == 0) best[row] = r;
        out_mu[(size_t)row * Zz + lane] = mu_e[(size_t)row * Zz + lane];
        out_lv[(size_t)row * Zz + lane] = lv_e[(size_t)row * Zz + lane];
        const float4* src = reinterpret_cast<const float4*>(&xhat[(size_t)row * Dd]);
        float4*       dst = reinterpret_cast<float4*>(&out_xh[(size_t)row * Dd]);
        dst[lane]      = src[lane];
        dst[lane + 64] = src[lane + 64];
    }
}

extern "C" void kernel_launch(void* const* d_in, const int* in_sizes, int n_in,
                              void* d_out, int out_size, void* d_ws, size_t ws_size,
                              hipStream_t stream)
{
    const float* x         = (const float*)d_in[0];
    const float* eps       = (const float*)d_in[1];
    const float* enc_in_w  = (const float*)d_in[2];
    const float* enc_in_b  = (const float*)d_in[3];
    const float* enc_hid_w = (const float*)d_in[4];
    const float* enc_hid_b = (const float*)d_in[5];
    const float* mu_w      = (const float*)d_in[6];
    const float* mu_b      = (const float*)d_in[7];
    const float* lv_w      = (const float*)d_in[8];
    const float* lv_b      = (const float*)d_in[9];
    const float* dec_in_w  = (const float*)d_in[10];
    const float* dec_in_b  = (const float*)d_in[11];
    const float* dec_hid_w = (const float*)d_in[12];
    const float* dec_hid_b = (const float*)d_in[13];
    const float* dec_out_w = (const float*)d_in[14];
    const float* dec_out_b = (const float*)d_in[15];

    float* ws   = (float*)d_ws;
    float* bufA = ws;                          // [B,H]
    float* bufB = bufA + (size_t)Bb * Hh;      // [B,H]
    float* mu_e = bufB + (size_t)Bb * Hh;      // [B,Z]
    float* lv_e = mu_e + (size_t)Bb * Zz;      // [B,Z]
    float* z_e  = lv_e + (size_t)Bb * Zz;      // [B,Z]
    float* rec  = z_e  + (size_t)Bb * Zz;      // [B]
    float* best = rec  + Bb;                   // [B]

    float* out_mu = (float*)d_out;
    float* out_lv = out_mu + (size_t)Bb * Zz;
    float* out_xh = out_lv + (size_t)Bb * Zz;

    const dim3 blk(256);
    const dim3 gBig(Bb / 128, Hh / 128);  // 128 x 4
    const dim3 gNar(Bb / 128, 1);
    const dim3 gRow(Bb / 4);
    const dim3 gZ(Bb * Zz / 4 / 256);

    for (int e = 0; e < Eexp; ++e) {
        // encoder
        sgemm_bias<128, true ><<<gBig, blk, 0, stream>>>(
            x, enc_in_w + (size_t)e * Dd * Hh, enc_in_b + (size_t)e * Hh,
            bufA, Bb, Hh, Dd);
        sgemm_bias<128, true ><<<gBig, blk, 0, stream>>>(
            bufA, enc_hid_w + ((size_t)e * 2 + 0) * Hh * Hh,
            enc_hid_b + ((size_t)e * 2 + 0) * Hh, bufB, Bb, Hh, Hh);
        sgemm_bias<128, true ><<<gBig, blk, 0, stream>>>(
            bufB, enc_hid_w + ((size_t)e * 2 + 1) * Hh * Hh,
            enc_hid_b + ((size_t)e * 2 + 1) * Hh, bufA, Bb, Hh, Hh);
        // heads
        sgemm_bias<64, false><<<gNar, blk, 0, stream>>>(
            bufA, mu_w + (size_t)e * Hh * Zz, mu_b + (size_t)e * Zz,
            mu_e, Bb, Zz, Hh);
        sgemm_bias<64, false><<<gNar, blk, 0, stream>>>(
            bufA, lv_w + (size_t)e * Hh * Zz, lv_b + (size_t)e * Zz,
            lv_e, Bb, Zz, Hh);
        // reparameterize
        z_kernel<<<gZ, blk, 0, stream>>>(
            (const float4*)mu_e, (const float4*)lv_e, (const float4*)eps, (float4*)z_e);
        // decoder
        sgemm_bias<128, true ><<<gBig, blk, 0, stream>>>(
            z_e, dec_in_w + (size_t)e * Zz * Hh, dec_in_b + (size_t)e * Hh,
            bufB, Bb, Hh, Zz);
        sgemm_bias<128, true ><<<gBig, blk, 0, stream>>>(
            bufB, dec_hid_w + ((size_t)e * 2 + 0) * Hh * Hh,
            dec_hid_b + ((size_t)e * 2 + 0) * Hh, bufA, Bb, Hh, Hh);
        sgemm_bias<128, true ><<<gBig, blk, 0, stream>>>(
            bufA, dec_hid_w + ((size_t)e * 2 + 1) * Hh * Hh,
            dec_hid_b + ((size_t)e * 2 + 1) * Hh, bufB, Bb, Hh, Hh);
        sgemm_bias<128, false><<<gBig, blk, 0, stream>>>(
            bufB, dec_out_w + (size_t)e * Hh * Dd, dec_out_b + (size_t)e * Dd,
            bufA, Bb, Dd, Hh);
        // recon + running-min gather
        recon_kernel<<<gRow, blk, 0, stream>>>(bufA, x, rec);
        select_kernel<<<gRow, blk, 0, stream>>>(
            rec, best, mu_e, lv_e, bufA, out_mu, out_lv, out_xh, e == 0 ? 1 : 0);
    }
}

// Round 2
// 1953.864 us; speedup vs baseline: 2.9762x; 2.9762x over previous
//
#include <hip/hip_runtime.h>
#include <cstdint>

#define Eexp 8
#define Bb   16384
#define Dd   512
#define Hh   512
#define Zz   64

typedef _Float16 f16x8 __attribute__((ext_vector_type(8)));
typedef _Float16 f16x4 __attribute__((ext_vector_type(4)));
typedef float    f32x4 __attribute__((ext_vector_type(4)));

// per-expert transposed-split weight region (elements), fixed layout
#define PEREXP     1671168
#define OFF_ENCIN  0
#define OFF_HID0   262144
#define OFF_HID1   524288
#define OFF_MU     786432
#define OFF_LV     819200
#define OFF_DECIN  851968
#define OFF_DHID0  884736
#define OFF_DHID1  1146880
#define OFF_DECOUT 1409024
#define WT_ELEMS   (8 * (size_t)PEREXP)

#define GLL16(g, l) __builtin_amdgcn_global_load_lds( \
    (const __attribute__((address_space(1))) void*)(g), \
    (__attribute__((address_space(3))) void*)(l), 16, 0, 0)

// ---------------------------------------------------------------------------
// Weight transpose + f16 hi/lo split:  src[K,N] fp32 -> dst[N,K] f16 (hi,lo)
// grid: (N/64, K/64, E). 64x64 tiles via padded-LDS transpose.
// ---------------------------------------------------------------------------
__global__ __launch_bounds__(256)
void tsplit(const float* __restrict__ src, _Float16* __restrict__ dH,
            _Float16* __restrict__ dL, int K, int N, long sStride, long dStride)
{
    __shared__ float t[64][65];
    const int e  = blockIdx.z;
    const int n0 = blockIdx.x * 64, k0 = blockIdx.y * 64;
    const float* S = src + (size_t)e * sStride;
    const int tid = threadIdx.x;
    const int rr = tid >> 4, cc = (tid & 15) * 4;
    #pragma unroll
    for (int p = 0; p < 4; ++p) {
        const float4 v = *reinterpret_cast<const float4*>(
            &S[(size_t)(k0 + rr + p * 16) * N + n0 + cc]);
        t[rr + p * 16][cc + 0] = v.x; t[rr + p * 16][cc + 1] = v.y;
        t[rr + p * 16][cc + 2] = v.z; t[rr + p * 16][cc + 3] = v.w;
    }
    __syncthreads();
    _Float16* DH = dH + (size_t)e * dStride;
    _Float16* DL = dL + (size_t)e * dStride;
    #pragma unroll
    for (int p = 0; p < 4; ++p) {
        const int no = rr + p * 16;
        const float a = t[cc + 0][no], b = t[cc + 1][no];
        const float c = t[cc + 2][no], d = t[cc + 3][no];
        const _Float16 ha = (_Float16)a, hb = (_Float16)b;
        const _Float16 hc = (_Float16)c, hd = (_Float16)d;
        f16x4 hv = {ha, hb, hc, hd};
        f16x4 lv = {(_Float16)(a - (float)ha), (_Float16)(b - (float)hb),
                    (_Float16)(c - (float)hc), (_Float16)(d - (float)hd)};
        *reinterpret_cast<f16x4*>(&DH[(size_t)(n0 + no) * K + k0 + cc]) = hv;
        *reinterpret_cast<f16x4*>(&DL[(size_t)(n0 + no) * K + k0 + cc]) = lv;
    }
}

// ---------------------------------------------------------------------------
// f16x2-split MFMA GEMM: C = A @ W + bias (optional ReLU).
// A[M,Ka] fp32 row-major (split in-kernel); WT_hi/lo [N,Ka] f16 (pre-split).
// BM=128, BK=32, 256 thr = 4 waves (2x2), wave tile 64 x (BN/2).
// XOR swizzle: 16B slot s of row r lives at s ^ ((r>>1)&3).
// DUAL: grid.y==1 selects second (W,bias,C) set — fused mu/lv.
// ---------------------------------------------------------------------------
template<int BN, bool RELU, bool DUAL>
__global__ __launch_bounds__(256, 2)
void gemm_f16x2(const float* __restrict__ A,
                const _Float16* __restrict__ Wh0, const _Float16* __restrict__ Wl0,
                const float* __restrict__ bias0, float* __restrict__ C0,
                const _Float16* __restrict__ Wh1, const _Float16* __restrict__ Wl1,
                const float* __restrict__ bias1, float* __restrict__ C1,
                int Ka, int Nout)
{
    constexpr int BM = 128, BK = 32;
    constexpr int WN = BN / 2;        // wave n-extent: 64 or 32
    constexpr int NF = WN / 16;       // 4 or 2
    __shared__ __align__(16) _Float16 Ah[BM * BK], Al[BM * BK];
    __shared__ __align__(16) _Float16 Wh[BN * BK], Wl[BN * BK];

    const _Float16* WhP = Wh0; const _Float16* WlP = Wl0;
    const float* biasP = bias0; float* CP = C0;
    if (DUAL && blockIdx.y == 1) { WhP = Wh1; WlP = Wl1; biasP = bias1; CP = C1; }

    const int tid  = threadIdx.x;
    const int lane = tid & 63;
    const int wid  = tid >> 6;
    const int wr = wid >> 1, wc = wid & 1;
    const int row0 = blockIdx.x * BM;
    const int col0 = DUAL ? 0 : blockIdx.y * BN;
    const int sr = tid >> 3, sc4 = tid & 7;   // A-staging map

    f32x4 acc[4][NF];
    #pragma unroll
    for (int i = 0; i < 4; ++i)
        #pragma unroll
        for (int j = 0; j < NF; ++j) acc[i][j] = {0.f, 0.f, 0.f, 0.f};

    for (int k0 = 0; k0 < Ka; k0 += BK) {
        __syncthreads();
        // ---- W tiles: global_load_lds, pre-swizzled per-lane source ----
        {
            constexpr int CPW = BN / 64;   // 1KB chunks per wave per component
            #pragma unroll
            for (int cch = 0; cch < CPW; ++cch) {
                const int q  = wid * CPW + cch;          // chunk: 16 rows
                const int rl = q * 16 + (lane >> 2);     // local row
                const int c  = (lane & 3) ^ ((rl >> 1) & 3);
                const size_t gi = (size_t)(col0 + rl) * Ka + k0 + c * 8;
                GLL16(WhP + gi, &Wh[q * 512]);
                GLL16(WlP + gi, &Wl[q * 512]);
            }
        }
        // ---- A tile: fp32 load, split to f16 hi/lo, swizzled ds_write ----
        #pragma unroll
        for (int p = 0; p < 4; ++p) {
            const int r = sr + p * 32;
            const float4 v = *reinterpret_cast<const float4*>(
                &A[(size_t)(row0 + r) * Ka + k0 + sc4 * 4]);
            const _Float16 h0 = (_Float16)v.x, h1 = (_Float16)v.y;
            const _Float16 h2 = (_Float16)v.z, h3 = (_Float16)v.w;
            f16x4 hv = {h0, h1, h2, h3};
            f16x4 lv = {(_Float16)(v.x - (float)h0), (_Float16)(v.y - (float)h1),
                        (_Float16)(v.z - (float)h2), (_Float16)(v.w - (float)h3)};
            const int cp  = (sc4 >> 1) ^ ((r >> 1) & 3);
            const int idx = r * 32 + cp * 8 + (sc4 & 1) * 4;
            *reinterpret_cast<f16x4*>(&Ah[idx]) = hv;
            *reinterpret_cast<f16x4*>(&Al[idx]) = lv;
        }
        __syncthreads();
        // ---- fragments + 3-term MFMA ----
        f16x8 fah[4], fal[4], fwh[NF], fwl[NF];
        #pragma unroll
        for (int mf = 0; mf < 4; ++mf) {
            const int r = wr * 64 + mf * 16 + (lane & 15);
            const int c = (lane >> 4) ^ ((r >> 1) & 3);
            const int idx = r * 32 + c * 8;
            fah[mf] = *reinterpret_cast<f16x8*>(&Ah[idx]);
            fal[mf] = *reinterpret_cast<f16x8*>(&Al[idx]);
        }
        #pragma unroll
        for (int nf = 0; nf < NF; ++nf) {
            const int r = wc * WN + nf * 16 + (lane & 15);
            const int c = (lane >> 4) ^ ((r >> 1) & 3);
            const int idx = r * 32 + c * 8;
            fwh[nf] = *reinterpret_cast<f16x8*>(&Wh[idx]);
            fwl[nf] = *reinterpret_cast<f16x8*>(&Wl[idx]);
        }
        #pragma unroll
        for (int mf = 0; mf < 4; ++mf)
            #pragma unroll
            for (int nf = 0; nf < NF; ++nf) {
                acc[mf][nf] = __builtin_amdgcn_mfma_f32_16x16x32_f16(
                    fah[mf], fwh[nf], acc[mf][nf], 0, 0, 0);
                acc[mf][nf] = __builtin_amdgcn_mfma_f32_16x16x32_f16(
                    fah[mf], fwl[nf], acc[mf][nf], 0, 0, 0);
                acc[mf][nf] = __builtin_amdgcn_mfma_f32_16x16x32_f16(
                    fal[mf], fwh[nf], acc[mf][nf], 0, 0, 0);
            }
    }
    // ---- epilogue: bias (+ReLU), fp32 out ----
    #pragma unroll
    for (int nf = 0; nf < NF; ++nf) {
        const int col = col0 + wc * WN + nf * 16 + (lane & 15);
        const float bv = biasP[col];
        #pragma unroll
        for (int mf = 0; mf < 4; ++mf)
            #pragma unroll
            for (int j = 0; j < 4; ++j) {
                const int rowg = row0 + wr * 64 + mf * 16 + (lane >> 4) * 4 + j;
                float v = acc[mf][nf][j] + bv;
                if (RELU) v = fmaxf(v, 0.f);
                CP[(size_t)rowg * Nout + col] = v;
            }
    }
}

// z = mu + exp(0.5*logvar)*eps
__global__ __launch_bounds__(256)
void z_kernel(const float4* __restrict__ mu, const float4* __restrict__ lv,
              const float4* __restrict__ eps, float4* __restrict__ z)
{
    const int i = blockIdx.x * 256 + threadIdx.x;
    const float4 m = mu[i], l = lv[i], e = eps[i];
    float4 r;
    r.x = m.x + expf(0.5f * l.x) * e.x;
    r.y = m.y + expf(0.5f * l.y) * e.y;
    r.z = m.z + expf(0.5f * l.z) * e.z;
    r.w = m.w + expf(0.5f * l.w) * e.w;
    z[i] = r;
}

__global__ __launch_bounds__(256)
void recon_kernel(const float* __restrict__ xhat, const float* __restrict__ x,
                  float* __restrict__ recon)
{
    const int wave = threadIdx.x >> 6;
    const int lane = threadIdx.x & 63;
    const int row  = blockIdx.x * 4 + wave;
    const float4* xh = reinterpret_cast<const float4*>(&xhat[(size_t)row * Dd]);
    const float4* xx = reinterpret_cast<const float4*>(&x[(size_t)row * Dd]);
    float s = 0.f;
    #pragma unroll
    for (int it = 0; it < 2; ++it) {
        const float4 a = xh[lane + it * 64];
        const float4 b = xx[lane + it * 64];
        float d;
        d = a.x - b.x; s = fmaf(d, d, s);
        d = a.y - b.y; s = fmaf(d, d, s);
        d = a.z - b.z; s = fmaf(d, d, s);
        d = a.w - b.w; s = fmaf(d, d, s);
    }
    #pragma unroll
    for (int off = 32; off > 0; off >>= 1) s += __shfl_down(s, off);
    if (lane == 0) recon[row] = s * (1.0f / 512.0f);
}

__global__ __launch_bounds__(256)
void select_kernel(const float* __restrict__ recon, float* __restrict__ best,
                   const float* __restrict__ mu_e, const float* __restrict__ lv_e,
                   const float* __restrict__ xhat,
                   float* __restrict__ out_mu, float* __restrict__ out_lv,
                   float* __restrict__ out_xh, int isFirst)
{
    const int wave = threadIdx.x >> 6;
    const int lane = threadIdx.x & 63;
    const int row  = blockIdx.x * 4 + wave;
    const float r  = recon[row];
    const bool cond = isFirst || (r < best[row]);
    if (cond) {
        if (lane == 0) best[row] = r;
        out_mu[(size_t)row * Zz + lane] = mu_e[(size_t)row * Zz + lane];
        out_lv[(size_t)row * Zz + lane] = lv_e[(size_t)row * Zz + lane];
        const float4* src = reinterpret_cast<const float4*>(&xhat[(size_t)row * Dd]);
        float4*       dst = reinterpret_cast<float4*>(&out_xh[(size_t)row * Dd]);
        dst[lane]      = src[lane];
        dst[lane + 64] = src[lane + 64];
    }
}

extern "C" void kernel_launch(void* const* d_in, const int* in_sizes, int n_in,
                              void* d_out, int out_size, void* d_ws, size_t ws_size,
                              hipStream_t stream)
{
    const float* x         = (const float*)d_in[0];
    const float* eps       = (const float*)d_in[1];
    const float* enc_in_w  = (const float*)d_in[2];
    const float* enc_in_b  = (const float*)d_in[3];
    const float* enc_hid_w = (const float*)d_in[4];
    const float* enc_hid_b = (const float*)d_in[5];
    const float* mu_w      = (const float*)d_in[6];
    const float* mu_b      = (const float*)d_in[7];
    const float* lv_w      = (const float*)d_in[8];
    const float* lv_b      = (const float*)d_in[9];
    const float* dec_in_w  = (const float*)d_in[10];
    const float* dec_in_b  = (const float*)d_in[11];
    const float* dec_hid_w = (const float*)d_in[12];
    const float* dec_hid_b = (const float*)d_in[13];
    const float* dec_out_w = (const float*)d_in[14];
    const float* dec_out_b = (const float*)d_in[15];

    _Float16* wtH = (_Float16*)d_ws;
    _Float16* wtL = wtH + WT_ELEMS;
    float* fbase  = (float*)(wtL + WT_ELEMS);
    float* bufA = fbase;                       // [B,H]
    float* bufB = bufA + (size_t)Bb * Hh;      // [B,H]
    float* mu_e = bufB + (size_t)Bb * Hh;      // [B,Z]
    float* lv_e = mu_e + (size_t)Bb * Zz;      // [B,Z]
    float* z_e  = lv_e + (size_t)Bb * Zz;      // [B,Z]
    float* rec  = z_e  + (size_t)Bb * Zz;      // [B]
    float* best = rec  + Bb;                   // [B]

    float* out_mu = (float*)d_out;
    float* out_lv = out_mu + (size_t)Bb * Zz;
    float* out_xh = out_lv + (size_t)Bb * Zz;

    const dim3 blk(256);

    // ---- one-time weight transpose+split into ws ----
    tsplit<<<dim3(8, 8, 8), blk, 0, stream>>>(enc_in_w,          wtH + OFF_ENCIN,  wtL + OFF_ENCIN,  512, 512, 262144, PEREXP);
    tsplit<<<dim3(8, 8, 8), blk, 0, stream>>>(enc_hid_w,         wtH + OFF_HID0,   wtL + OFF_HID0,   512, 512, 524288, PEREXP);
    tsplit<<<dim3(8, 8, 8), blk, 0, stream>>>(enc_hid_w + 262144, wtH + OFF_HID1,  wtL + OFF_HID1,   512, 512, 524288, PEREXP);
    tsplit<<<dim3(1, 8, 8), blk, 0, stream>>>(mu_w,              wtH + OFF_MU,     wtL + OFF_MU,     512,  64,  32768, PEREXP);
    tsplit<<<dim3(1, 8, 8), blk, 0, stream>>>(lv_w,              wtH + OFF_LV,     wtL + OFF_LV,     512,  64,  32768, PEREXP);
    tsplit<<<dim3(8, 1, 8), blk, 0, stream>>>(dec_in_w,          wtH + OFF_DECIN,  wtL + OFF_DECIN,   64, 512,  32768, PEREXP);
    tsplit<<<dim3(8, 8, 8), blk, 0, stream>>>(dec_hid_w,         wtH + OFF_DHID0,  wtL + OFF_DHID0,  512, 512, 524288, PEREXP);
    tsplit<<<dim3(8, 8, 8), blk, 0, stream>>>(dec_hid_w + 262144, wtH + OFF_DHID1, wtL + OFF_DHID1,  512, 512, 524288, PEREXP);
    tsplit<<<dim3(8, 8, 8), blk, 0, stream>>>(dec_out_w,         wtH + OFF_DECOUT, wtL + OFF_DECOUT, 512, 512, 262144, PEREXP);

    const dim3 gBig(Bb / 128, 4);
    const dim3 gDual(Bb / 128, 2);
    const dim3 gRow(Bb / 4);
    const dim3 gZ(Bb * Zz / 4 / 256);

    for (int e = 0; e < Eexp; ++e) {
        const size_t wo = (size_t)e * PEREXP;
        gemm_f16x2<128, true , false><<<gBig, blk, 0, stream>>>(
            x, wtH + wo + OFF_ENCIN, wtL + wo + OFF_ENCIN,
            enc_in_b + (size_t)e * Hh, bufA,
            nullptr, nullptr, nullptr, nullptr, Dd, Hh);
        gemm_f16x2<128, true , false><<<gBig, blk, 0, stream>>>(
            bufA, wtH + wo + OFF_HID0, wtL + wo + OFF_HID0,
            enc_hid_b + ((size_t)e * 2 + 0) * Hh, bufB,
            nullptr, nullptr, nullptr, nullptr, Hh, Hh);
        gemm_f16x2<128, true , false><<<gBig, blk, 0, stream>>>(
            bufB, wtH + wo + OFF_HID1, wtL + wo + OFF_HID1,
            enc_hid_b + ((size_t)e * 2 + 1) * Hh, bufA,
            nullptr, nullptr, nullptr, nullptr, Hh, Hh);
        gemm_f16x2<64, false, true ><<<gDual, blk, 0, stream>>>(
            bufA, wtH + wo + OFF_MU, wtL + wo + OFF_MU,
            mu_b + (size_t)e * Zz, mu_e,
            wtH + wo + OFF_LV, wtL + wo + OFF_LV,
            lv_b + (size_t)e * Zz, lv_e, Hh, Zz);
        z_kernel<<<gZ, blk, 0, stream>>>(
            (const float4*)mu_e, (const float4*)lv_e, (const float4*)eps, (float4*)z_e);
        gemm_f16x2<128, true , false><<<gBig, blk, 0, stream>>>(
            z_e, wtH + wo + OFF_DECIN, wtL + wo + OFF_DECIN,
            dec_in_b + (size_t)e * Hh, bufB,
            nullptr, nullptr, nullptr, nullptr, Zz, Hh);
        gemm_f16x2<128, true , false><<<gBig, blk, 0, stream>>>(
            bufB, wtH + wo + OFF_DHID0, wtL + wo + OFF_DHID0,
            dec_hid_b + ((size_t)e * 2 + 0) * Hh, bufA,
            nullptr, nullptr, nullptr, nullptr, Hh, Hh);
        gemm_f16x2<128, true , false><<<gBig, blk, 0, stream>>>(
            bufA, wtH + wo + OFF_DHID1, wtL + wo + OFF_DHID1,
            dec_hid_b + ((size_t)e * 2 + 1) * Hh, bufB,
            nullptr, nullptr, nullptr, nullptr, Hh, Hh);
        gemm_f16x2<128, false, false><<<gBig, blk, 0, stream>>>(
            bufB, wtH + wo + OFF_DECOUT, wtL + wo + OFF_DECOUT,
            dec_out_b + (size_t)e * Dd, bufA,
            nullptr, nullptr, nullptr, nullptr, Hh, Dd);
        recon_kernel<<<gRow, blk, 0, stream>>>(bufA, x, rec);
        select_kernel<<<gRow, blk, 0, stream>>>(
            rec, best, mu_e, lv_e, bufA, out_mu, out_lv, out_xh, e == 0 ? 1 : 0);
    }
}